// Round 4
// baseline (1184.644 us; speedup 1.0000x reference)
//
#include <hip/hip_runtime.h>
#include <hip/hip_bf16.h>
#include <math.h>

// Problem constants (NodeEncoder: 3-layer GAT on chess graph)
#define N_NODES 32768
#define E_PER   16384
#define T_TYPES 8
#define E_TYPED (T_TYPES * E_PER)      // 131072
#define E_TOT   (E_TYPED + N_NODES)    // 163840 (with self loops)
#define NEG_SLOPE 0.2f
#define CH2 16384                       // layer-2 node chunk
#define CH3 8192                        // layer-3 node chunk

// ---------- helpers ----------
__device__ __forceinline__ float lrelu(float a) { return a > 0.0f ? a : NEG_SLOPE * a; }

__device__ __forceinline__ void osm_upd(float& m, float& z, float a) {
  if (a > m) { z = z * __expf(m - a) + 1.0f; m = a; }
  else       { z += __expf(a - m); }
}
__device__ __forceinline__ void osm_comb(float& m, float& z, int off) {
  float om = __shfl_xor(m, off, 64);
  float oz = __shfl_xor(z, off, 64);
  float nm = fmaxf(m, om);
  z = z * __expf(m - nm) + oz * __expf(om - nm);
  m = nm;
}

// ---------- CSR build (by dst) ----------
__global__ __launch_bounds__(256) void k_deg(const int* __restrict__ ei, int* __restrict__ deg) {
  int e = blockIdx.x * 256 + threadIdx.x;  // grid sized exactly E_TOT/256
  int dst;
  if (e < E_TYPED) { int t = e >> 14; int j = e & (E_PER - 1); dst = ei[(2 * t + 1) * E_PER + j]; }
  else dst = e - E_TYPED;
  atomicAdd(deg + (dst & (N_NODES - 1)), 1);
}

// exclusive scan of 32768 counts, one 1024-thread block (32/thread).
// deg / ofs / cur are DISTINCT buffers (no aliasing).
__global__ __launch_bounds__(1024) void k_scan(const int* deg, int* ofs, int* cur) {
  __shared__ int part[1024];
  int tid = threadIdx.x;
  int base = tid * 32;
  int loc[32];
  int run = 0;
#pragma unroll
  for (int j = 0; j < 32; ++j) { loc[j] = run; run += deg[base + j]; }
  part[tid] = run;
  int self = run;
  __syncthreads();
  for (int off = 1; off < 1024; off <<= 1) {
    int v = (tid >= off) ? part[tid - off] : 0;
    __syncthreads();
    part[tid] += v;
    __syncthreads();
  }
  int excl = part[tid] - self;
#pragma unroll
  for (int j = 0; j < 32; ++j) { int v = excl + loc[j]; ofs[base + j] = v; cur[base + j] = v; }
  if (tid == 1023) ofs[N_NODES] = part[1023];
}

__global__ __launch_bounds__(256) void k_fill(const int* __restrict__ ei, int* __restrict__ cur,
                                              int* __restrict__ csr) {
  int e = blockIdx.x * 256 + threadIdx.x;
  int src, dst, t;
  if (e < E_TYPED) { t = e >> 14; int j = e & (E_PER - 1); src = ei[2 * t * E_PER + j]; dst = ei[(2 * t + 1) * E_PER + j]; }
  else { src = dst = e - E_TYPED; t = 8; }
  int pos = atomicAdd(cur + (dst & (N_NODES - 1)), 1);
  if (pos >= 0 && pos < E_TOT)
    csr[pos] = (src & (N_NODES - 1)) | (t << 16);
}

// ---------- per-layer folded attention vectors ----------
// prep layout (floats): [0..511] v_src[h*128+i], [512..1023] v_dst[h*128+i],
//                       [1024..1059] s_edge[t*4+h], t=0..8 (8 = self loop)
__global__ void k_prep(const float* __restrict__ W, const float* __restrict__ We,
                       const float* __restrict__ asrc, const float* __restrict__ adst,
                       const float* __restrict__ aedge, float* __restrict__ prep,
                       int din, int dout) {
  int task = blockIdx.x * blockDim.x + threadIdx.x;
  int hd = 4 * din;
  if (task < hd) {
    int h = task / din, i = task % din;
    float s = 0.0f;
    for (int c = 0; c < dout; ++c)
      s += W[(size_t)i * 4 * dout + h * dout + c] * asrc[h * dout + c];
    prep[h * 128 + i] = s;
  } else if (task < 2 * hd) {
    int k = task - hd; int h = k / din, i = k % din;
    float s = 0.0f;
    for (int c = 0; c < dout; ++c)
      s += W[(size_t)i * 4 * dout + h * dout + c] * adst[h * dout + c];
    prep[512 + h * 128 + i] = s;
  } else if (task < 2 * hd + 32) {
    int k = task - 2 * hd; int t = k >> 2, h = k & 3;
    float s = 0.0f;
    for (int c = 0; c < dout; ++c)
      s += We[(size_t)t * 4 * dout + h * dout + c] * aedge[h * dout + c];
    prep[1024 + t * 4 + h] = s;
  } else if (task < 2 * hd + 36) {
    int h = task - 2 * hd - 32;
    float s = 0.0f;
    for (int t = 0; t < 8; ++t)
      for (int c = 0; c < dout; ++c)
        s += We[(size_t)t * 4 * dout + h * dout + c] * aedge[h * dout + c];
    prep[1024 + 32 + h] = s * 0.125f;   // loop edge attr = mean one-hot
  }
}

// ---------- per-node scores: s_src[n][h], s_dst[n][h] (wave per node) ----------
template <int DIN>
__global__ __launch_bounds__(256) void k_scores(const float* __restrict__ hin,
                                                const float* __restrict__ prep,
                                                float* __restrict__ s_src,
                                                float* __restrict__ s_dst) {
  __shared__ float vv[8 * DIN];
  int tid = threadIdx.x;
  for (int j = tid; j < 8 * DIN; j += 256) {
    int s = j / DIN, i = j % DIN;
    vv[j] = prep[(s & 3) * 128 + i + ((s >= 4) ? 512 : 0)];
  }
  __syncthreads();
  int lane = tid & 63, wv = tid >> 6;
  int n = blockIdx.x * 4 + wv;
  const float* row = hin + (size_t)n * DIN;
  float p0 = 0, p1 = 0, p2 = 0, p3 = 0, p4 = 0, p5 = 0, p6 = 0, p7 = 0;
  for (int c = lane; c < DIN; c += 64) {
    float v = row[c];
    p0 += v * vv[0 * DIN + c]; p1 += v * vv[1 * DIN + c];
    p2 += v * vv[2 * DIN + c]; p3 += v * vv[3 * DIN + c];
    p4 += v * vv[4 * DIN + c]; p5 += v * vv[5 * DIN + c];
    p6 += v * vv[6 * DIN + c]; p7 += v * vv[7 * DIN + c];
  }
#pragma unroll
  for (int off = 32; off >= 1; off >>= 1) {
    p0 += __shfl_xor(p0, off, 64); p1 += __shfl_xor(p1, off, 64);
    p2 += __shfl_xor(p2, off, 64); p3 += __shfl_xor(p3, off, 64);
    p4 += __shfl_xor(p4, off, 64); p5 += __shfl_xor(p5, off, 64);
    p6 += __shfl_xor(p6, off, 64); p7 += __shfl_xor(p7, off, 64);
  }
  if (lane == 0) {
    float* a = s_src + (size_t)n * 4; a[0] = p0; a[1] = p1; a[2] = p2; a[3] = p3;
    float* b = s_dst + (size_t)n * 4; b[0] = p4; b[1] = p5; b[2] = p6; b[3] = p7;
  }
}

// ---------- softmax + input-space aggregation (wave per dst node) ----------
// agg[(n-n0)][h*DIN + c] = sum_e w[e,h] * h_in[src_e][c]   (fp32)
template <int DIN>
__global__ __launch_bounds__(256) void k_attn_agg(const float* __restrict__ hin,
                                                  const int* __restrict__ csr,
                                                  const int* __restrict__ ofs,
                                                  const float* __restrict__ prep,
                                                  const float* __restrict__ s_src,
                                                  const float* __restrict__ s_dst,
                                                  float* __restrict__ agg, int n0) {
  constexpr int ACC = (4 * DIN) / 64;   // 1 / 2 / 8
  __shared__ float se[68];              // 36 used, zero-padded to 64 type-slots
  int tid = threadIdx.x, lane = tid & 63, wv = tid >> 6;
  for (int j = tid; j < 68; j += 256) se[j] = (j < 36) ? prep[1024 + j] : 0.0f;
  __syncthreads();
  int n = n0 + blockIdx.x * 4 + wv;
  int o0 = ofs[n];
  int kd = ofs[n + 1] - o0;
  kd = max(0, min(kd, E_TOT));
  if (o0 < 0) o0 = 0; if (o0 > E_TOT - 1) o0 = E_TOT - 1;
  const float* sdp = s_dst + (size_t)n * 4;
  float sd0 = sdp[0], sd1 = sdp[1], sd2 = sdp[2], sd3 = sdp[3];

  float m0 = -1e30f, m1 = -1e30f, m2 = -1e30f, m3 = -1e30f;
  float z0 = 0, z1 = 0, z2 = 0, z3 = 0;
  for (int i = lane; i < kd; i += 64) {
    int ent = csr[o0 + i];
    int sx = ent & (N_NODES - 1);
    int tt = (ent >> 16) & 15;
    const float4 sv = *reinterpret_cast<const float4*>(s_src + (size_t)sx * 4);
    float a0 = lrelu(sv.x + sd0 + se[tt * 4 + 0]);
    float a1 = lrelu(sv.y + sd1 + se[tt * 4 + 1]);
    float a2 = lrelu(sv.z + sd2 + se[tt * 4 + 2]);
    float a3 = lrelu(sv.w + sd3 + se[tt * 4 + 3]);
    osm_upd(m0, z0, a0); osm_upd(m1, z1, a1); osm_upd(m2, z2, a2); osm_upd(m3, z3, a3);
  }
#pragma unroll
  for (int off = 32; off >= 1; off >>= 1) {
    osm_comb(m0, z0, off); osm_comb(m1, z1, off);
    osm_comb(m2, z2, off); osm_comb(m3, z3, off);
  }
  float r0 = (z0 > 0.0f) ? 1.0f / z0 : 0.0f;
  float r1 = (z1 > 0.0f) ? 1.0f / z1 : 0.0f;
  float r2 = (z2 > 0.0f) ? 1.0f / z2 : 0.0f;
  float r3 = (z3 > 0.0f) ? 1.0f / z3 : 0.0f;

  float acc[ACC];
#pragma unroll
  for (int q = 0; q < ACC; ++q) acc[q] = 0.0f;

  for (int b0 = 0; b0 < kd; b0 += 64) {
    int i = b0 + lane;
    int sx = 0; float w0 = 0, w1 = 0, w2 = 0, w3 = 0;
    if (i < kd) {
      int ent = csr[o0 + i];
      sx = ent & (N_NODES - 1);
      int tt = (ent >> 16) & 15;
      const float4 sv = *reinterpret_cast<const float4*>(s_src + (size_t)sx * 4);
      w0 = __expf(lrelu(sv.x + sd0 + se[tt * 4 + 0]) - m0) * r0;
      w1 = __expf(lrelu(sv.y + sd1 + se[tt * 4 + 1]) - m1) * r1;
      w2 = __expf(lrelu(sv.z + sd2 + se[tt * 4 + 2]) - m2) * r2;
      w3 = __expf(lrelu(sv.w + sd3 + se[tt * 4 + 3]) - m3) * r3;
    }
    int cnt = min(64, kd - b0);
    for (int e = 0; e < cnt; ++e) {
      int se_ = __shfl(sx, e, 64);
      float u0 = __shfl(w0, e, 64), u1 = __shfl(w1, e, 64);
      float u2 = __shfl(w2, e, 64), u3 = __shfl(w3, e, 64);
      const float* row = hin + (size_t)se_ * DIN;
      if constexpr (DIN == 128) {
        float v0 = row[lane];
        float v1 = row[64 + lane];
        acc[0] += u0 * v0; acc[1] += u0 * v1;
        acc[2] += u1 * v0; acc[3] += u1 * v1;
        acc[4] += u2 * v0; acc[5] += u2 * v1;
        acc[6] += u3 * v0; acc[7] += u3 * v1;
      } else if constexpr (DIN == 32) {
        float v = row[lane & 31];
        bool hi = lane >= 32;
        float wa = hi ? u1 : u0;
        float wb = hi ? u3 : u2;
        acc[0] += wa * v; acc[1] += wb * v;
      } else {
        float v = row[lane & 15];
        int hh = lane >> 4;
        float wa = (hh == 0) ? u0 : (hh == 1) ? u1 : (hh == 2) ? u2 : u3;
        acc[0] += wa * v;
      }
    }
  }

  float* ar = agg + (size_t)(n - n0) * (4 * DIN);
  if constexpr (DIN == 128) {
#pragma unroll
    for (int h = 0; h < 4; ++h) {
      ar[h * 128 + lane]      = acc[2 * h];
      ar[h * 128 + 64 + lane] = acc[2 * h + 1];
    }
  } else if constexpr (DIN == 32) {
    ar[lane]      = acc[0];   // (h=lane>>5)*32 + (lane&31) == lane
    ar[64 + lane] = acc[1];
  } else {
    ar[lane] = acc[0];        // (lane>>4)*16 + (lane&15) == lane
  }
}

// ---------- GEMM: out[m0+m][j] = act( 0.25 * sum_k agg[m][k] * Wv[k][j] + b[j] ) ----------
// Wv[k][j] with k = h*DIN+i maps to W[i][h*DOUT+j] (on-the-fly index)
template <int BM, int BN, int BK, int TM, int TN, int NT, int DIN, int DOUT, bool RELU>
__global__ __launch_bounds__(NT) void k_gemm(const float* __restrict__ A,
                                             const float* __restrict__ W,
                                             const float* __restrict__ bias,
                                             float* __restrict__ out, int m0) {
  constexpr int K = 4 * DIN;
  constexpr int LDA = BM + 4;
  constexpr int LDB = BN + 4;
  __shared__ __align__(16) float As[BK * LDA];   // transposed: As[k][m]
  __shared__ __align__(16) float Bs[BK * LDB];
  const int tid = threadIdx.x;
  const int tx = tid % (BN / TN);
  const int ty = tid / (BN / TN);
  const int mb = blockIdx.y * BM;     // chunk-local row base
  const int jb = blockIdx.x * BN;
  float acc[TM][TN] = {};
  constexpr int ITA = (BM * BK) / (NT * 4);
  constexpr int ITB = (BK * BN) / (NT * 4);
  for (int kb = 0; kb < K; kb += BK) {
#pragma unroll
    for (int it = 0; it < ITA; ++it) {
      int f = it * NT * 4 + tid * 4;
      int r = f / BK, c = f % BK;
      float4 u = *reinterpret_cast<const float4*>(A + (size_t)(mb + r) * K + kb + c);
      As[(c + 0) * LDA + r] = u.x;
      As[(c + 1) * LDA + r] = u.y;
      As[(c + 2) * LDA + r] = u.z;
      As[(c + 3) * LDA + r] = u.w;
    }
#pragma unroll
    for (int it = 0; it < ITB; ++it) {
      int f = it * NT * 4 + tid * 4;
      int kk = f / BN, jj = f % BN;
      int k = kb + kk; int h = k / DIN; int i = k % DIN;
      float4 u = *reinterpret_cast<const float4*>(W + (size_t)i * 4 * DOUT + h * DOUT + jb + jj);
      Bs[kk * LDB + jj + 0] = u.x;
      Bs[kk * LDB + jj + 1] = u.y;
      Bs[kk * LDB + jj + 2] = u.z;
      Bs[kk * LDB + jj + 3] = u.w;
    }
    __syncthreads();
#pragma unroll
    for (int kk = 0; kk < BK; ++kk) {
      float a_[TM], b_[TN];
#pragma unroll
      for (int q = 0; q < TM / 4; ++q) {
        float4 v = *reinterpret_cast<const float4*>(&As[kk * LDA + ty * TM + q * 4]);
        a_[q * 4 + 0] = v.x; a_[q * 4 + 1] = v.y; a_[q * 4 + 2] = v.z; a_[q * 4 + 3] = v.w;
      }
#pragma unroll
      for (int q = 0; q < TN / 4; ++q) {
        float4 v = *reinterpret_cast<const float4*>(&Bs[kk * LDB + tx * TN + q * 4]);
        b_[q * 4 + 0] = v.x; b_[q * 4 + 1] = v.y; b_[q * 4 + 2] = v.z; b_[q * 4 + 3] = v.w;
      }
#pragma unroll
      for (int ii = 0; ii < TM; ++ii)
#pragma unroll
        for (int jj = 0; jj < TN; ++jj)
          acc[ii][jj] = fmaf(a_[ii], b_[jj], acc[ii][jj]);
    }
    __syncthreads();
  }
#pragma unroll
  for (int ii = 0; ii < TM; ++ii) {
    int m = mb + ty * TM + ii;
#pragma unroll
    for (int jj = 0; jj < TN; ++jj) {
      int j = jb + tx * TN + jj;
      float v = acc[ii][jj] * 0.25f + bias[j];
      if (RELU) v = fmaxf(v, 0.0f);
      if (!isfinite(v)) v = 0.0f;      // diagnostic guard; no-op when correct
      out[(size_t)(m0 + m) * DOUT + j] = v;
    }
  }
}

// ---------- launch ----------
extern "C" void kernel_launch(void* const* d_in, const int* in_sizes, int n_in,
                              void* d_out, int out_size, void* d_ws, size_t ws_size,
                              hipStream_t stream) {
  (void)in_sizes; (void)n_in; (void)out_size; (void)ws_size;
  const float* x   = (const float*)d_in[0];
  const int*   ei  = (const int*)d_in[1];
  const float* W1  = (const float*)d_in[2];
  const float* We1 = (const float*)d_in[3];
  const float* as1 = (const float*)d_in[4];
  const float* ad1 = (const float*)d_in[5];
  const float* ae1 = (const float*)d_in[6];
  const float* b1  = (const float*)d_in[7];
  const float* W2  = (const float*)d_in[8];
  const float* We2 = (const float*)d_in[9];
  const float* as2 = (const float*)d_in[10];
  const float* ad2 = (const float*)d_in[11];
  const float* ae2 = (const float*)d_in[12];
  const float* b2  = (const float*)d_in[13];
  const float* W3  = (const float*)d_in[14];
  const float* We3 = (const float*)d_in[15];
  const float* as3 = (const float*)d_in[16];
  const float* ad3 = (const float*)d_in[17];
  const float* ae3 = (const float*)d_in[18];
  const float* b3  = (const float*)d_in[19];

  // workspace layout (~38 MB, 256B-aligned offsets)
  char* p = (char*)d_ws;
  int* ofs    = (int*)(p + 0);           // (N+1)*4 -> reserve 131328
  int* deg    = (int*)(p + 131328);      // 131072
  int* cur    = (int*)(p + 262400);      // 131072
  int* csr    = (int*)(p + 393472);      // 655360
  float* ssrc = (float*)(p + 1048832);   // 524288   [N][4]
  float* sdst = (float*)(p + 1573120);   // 524288   [N][4]
  float* prep = (float*)(p + 2097408);   // 4608
  float* h1   = (float*)(p + 2102016);   // 4194304  [N][32]
  float* h2   = (float*)(p + 6296320);   // 16777216 [N][128]
  float* agg  = (float*)(p + 23073536);  // 16777216 max( [N][64], [CH2][128], [CH3][512] )
  // end: 39850752 B

  // ---- CSR by dst (shared by all 3 layers) ----
  hipMemsetAsync(deg, 0, N_NODES * 4, stream);
  k_deg <<<E_TOT / 256, 256, 0, stream>>>(ei, deg);
  k_scan<<<1, 1024, 0, stream>>>(deg, ofs, cur);
  k_fill<<<E_TOT / 256, 256, 0, stream>>>(ei, cur, csr);

  // ---- layer 1: din=16, dout=32 ----
  k_prep<<<1, 256, 0, stream>>>(W1, We1, as1, ad1, ae1, prep, 16, 32);
  k_scores<16><<<N_NODES / 4, 256, 0, stream>>>(x, prep, ssrc, sdst);
  k_attn_agg<16><<<N_NODES / 4, 256, 0, stream>>>(x, csr, ofs, prep, ssrc, sdst, agg, 0);
  k_gemm<64, 32, 16, 4, 4, 128, 16, 32, true>
      <<<dim3(1, N_NODES / 64), 128, 0, stream>>>(agg, W1, b1, h1, 0);

  // ---- layer 2: din=32, dout=128, chunked ----
  k_prep<<<2, 256, 0, stream>>>(W2, We2, as2, ad2, ae2, prep, 32, 128);
  k_scores<32><<<N_NODES / 4, 256, 0, stream>>>(h1, prep, ssrc, sdst);
  for (int c0 = 0; c0 < N_NODES; c0 += CH2) {
    k_attn_agg<32><<<CH2 / 4, 256, 0, stream>>>(h1, csr, ofs, prep, ssrc, sdst, agg, c0);
    k_gemm<128, 128, 8, 8, 8, 256, 32, 128, true>
        <<<dim3(1, CH2 / 128), 256, 0, stream>>>(agg, W2, b2, h2, c0);
  }

  // ---- layer 3: din=128, dout=512 (no relu), chunked ----
  k_prep<<<5, 256, 0, stream>>>(W3, We3, as3, ad3, ae3, prep, 128, 512);
  k_scores<128><<<N_NODES / 4, 256, 0, stream>>>(h2, prep, ssrc, sdst);
  for (int c0 = 0; c0 < N_NODES; c0 += CH3) {
    k_attn_agg<128><<<CH3 / 4, 256, 0, stream>>>(h2, csr, ofs, prep, ssrc, sdst, agg, c0);
    k_gemm<128, 128, 8, 8, 8, 256, 128, 512, false>
        <<<dim3(512 / 128, CH3 / 128), 256, 0, stream>>>(agg, W3, b3, (float*)d_out, c0);
  }
}

// Round 5
// 795.353 us; speedup vs baseline: 1.4895x; 1.4895x over previous
//
#include <hip/hip_runtime.h>
#include <hip/hip_bf16.h>
#include <math.h>

// Problem constants (NodeEncoder: 3-layer GAT on chess graph)
#define N_NODES 32768
#define E_PER   16384
#define T_TYPES 8
#define E_TYPED (T_TYPES * E_PER)      // 131072
#define E_TOT   (E_TYPED + N_NODES)    // 163840 (with self loops)
#define NEG_SLOPE 0.2f
#define CH2 16384                       // layer-2 node chunk
#define CH3 8192                        // layer-3 node chunk

// ---------- helpers ----------
__device__ __forceinline__ float lrelu(float a) { return a > 0.0f ? a : NEG_SLOPE * a; }

__device__ __forceinline__ void osm_upd(float& m, float& z, float a) {
  if (a > m) { z = z * __expf(m - a) + 1.0f; m = a; }
  else       { z += __expf(a - m); }
}
__device__ __forceinline__ void osm_comb(float& m, float& z, int off) {
  float om = __shfl_xor(m, off, 64);
  float oz = __shfl_xor(z, off, 64);
  float nm = fmaxf(m, om);
  z = z * __expf(m - nm) + oz * __expf(om - nm);
  m = nm;
}

// ---------- CSR build (by dst) ----------
__global__ __launch_bounds__(256) void k_deg(const int* __restrict__ ei, int* __restrict__ deg) {
  int e = blockIdx.x * 256 + threadIdx.x;  // grid sized exactly E_TOT/256
  int dst;
  if (e < E_TYPED) { int t = e >> 14; int j = e & (E_PER - 1); dst = ei[(2 * t + 1) * E_PER + j]; }
  else dst = e - E_TYPED;
  atomicAdd(deg + (dst & (N_NODES - 1)), 1);
}

// exclusive scan of 32768 counts, one 1024-thread block (32/thread).
// deg / ofs / cur are DISTINCT buffers (no aliasing).
__global__ __launch_bounds__(1024) void k_scan(const int* deg, int* ofs, int* cur) {
  __shared__ int part[1024];
  int tid = threadIdx.x;
  int base = tid * 32;
  int loc[32];
  int run = 0;
#pragma unroll
  for (int j = 0; j < 32; ++j) { loc[j] = run; run += deg[base + j]; }
  part[tid] = run;
  int self = run;
  __syncthreads();
  for (int off = 1; off < 1024; off <<= 1) {
    int v = (tid >= off) ? part[tid - off] : 0;
    __syncthreads();
    part[tid] += v;
    __syncthreads();
  }
  int excl = part[tid] - self;
#pragma unroll
  for (int j = 0; j < 32; ++j) { int v = excl + loc[j]; ofs[base + j] = v; cur[base + j] = v; }
  if (tid == 1023) ofs[N_NODES] = part[1023];
}

__global__ __launch_bounds__(256) void k_fill(const int* __restrict__ ei, int* __restrict__ cur,
                                              int* __restrict__ csr) {
  int e = blockIdx.x * 256 + threadIdx.x;
  int src, dst, t;
  if (e < E_TYPED) { t = e >> 14; int j = e & (E_PER - 1); src = ei[2 * t * E_PER + j]; dst = ei[(2 * t + 1) * E_PER + j]; }
  else { src = dst = e - E_TYPED; t = 8; }
  int pos = atomicAdd(cur + (dst & (N_NODES - 1)), 1);
  if (pos >= 0 && pos < E_TOT)
    csr[pos] = (src & (N_NODES - 1)) | (t << 16);
}

// ---------- per-layer folded attention vectors (ONE WAVE PER OUTPUT) ----------
// prep layout (floats): [0..511] v_src[h*128+i], [512..1023] v_dst[h*128+i],
//                       [1024..1059] s_edge[t*4+h], t=0..8 (8 = self loop)
// Round-4 fix: old version ran 1-5 blocks with serial dependent-load loops
// (330 us each, 0.05% occupancy). Now: wave per output, lane-parallel c.
__global__ __launch_bounds__(256) void k_prep(const float* __restrict__ W,
                                              const float* __restrict__ We,
                                              const float* __restrict__ asrc,
                                              const float* __restrict__ adst,
                                              const float* __restrict__ aedge,
                                              float* __restrict__ prep,
                                              int din, int dout) {
  int task = (blockIdx.x * 256 + threadIdx.x) >> 6;
  int lane = threadIdx.x & 63;
  int hd = 4 * din;
  float s = 0.0f;
  if (task < 2 * hd) {
    int k = (task < hd) ? task : task - hd;
    int h = k / din, i = k % din;
    const float* a = (task < hd) ? asrc : adst;
    for (int c = lane; c < dout; c += 64)
      s += W[(size_t)i * 4 * dout + h * dout + c] * a[h * dout + c];
#pragma unroll
    for (int off = 32; off >= 1; off >>= 1) s += __shfl_xor(s, off, 64);
    if (lane == 0) prep[((task < hd) ? 0 : 512) + h * 128 + i] = s;
  } else if (task < 2 * hd + 32) {
    int k = task - 2 * hd; int t = k >> 2, h = k & 3;
    for (int c = lane; c < dout; c += 64)
      s += We[(size_t)t * 4 * dout + h * dout + c] * aedge[h * dout + c];
#pragma unroll
    for (int off = 32; off >= 1; off >>= 1) s += __shfl_xor(s, off, 64);
    if (lane == 0) prep[1024 + t * 4 + h] = s;
  } else if (task < 2 * hd + 36) {
    int h = task - 2 * hd - 32;
    for (int t = 0; t < 8; ++t)
      for (int c = lane; c < dout; c += 64)
        s += We[(size_t)t * 4 * dout + h * dout + c] * aedge[h * dout + c];
#pragma unroll
    for (int off = 32; off >= 1; off >>= 1) s += __shfl_xor(s, off, 64);
    if (lane == 0) prep[1024 + 32 + h] = s * 0.125f;   // loop edge attr = mean one-hot
  }
}

// ---------- per-node scores: s_src[n][h], s_dst[n][h] (wave per node) ----------
template <int DIN>
__global__ __launch_bounds__(256) void k_scores(const float* __restrict__ hin,
                                                const float* __restrict__ prep,
                                                float* __restrict__ s_src,
                                                float* __restrict__ s_dst) {
  __shared__ float vv[8 * DIN];
  int tid = threadIdx.x;
  for (int j = tid; j < 8 * DIN; j += 256) {
    int s = j / DIN, i = j % DIN;
    vv[j] = prep[(s & 3) * 128 + i + ((s >= 4) ? 512 : 0)];
  }
  __syncthreads();
  int lane = tid & 63, wv = tid >> 6;
  int n = blockIdx.x * 4 + wv;
  const float* row = hin + (size_t)n * DIN;
  float p0 = 0, p1 = 0, p2 = 0, p3 = 0, p4 = 0, p5 = 0, p6 = 0, p7 = 0;
  for (int c = lane; c < DIN; c += 64) {
    float v = row[c];
    p0 += v * vv[0 * DIN + c]; p1 += v * vv[1 * DIN + c];
    p2 += v * vv[2 * DIN + c]; p3 += v * vv[3 * DIN + c];
    p4 += v * vv[4 * DIN + c]; p5 += v * vv[5 * DIN + c];
    p6 += v * vv[6 * DIN + c]; p7 += v * vv[7 * DIN + c];
  }
#pragma unroll
  for (int off = 32; off >= 1; off >>= 1) {
    p0 += __shfl_xor(p0, off, 64); p1 += __shfl_xor(p1, off, 64);
    p2 += __shfl_xor(p2, off, 64); p3 += __shfl_xor(p3, off, 64);
    p4 += __shfl_xor(p4, off, 64); p5 += __shfl_xor(p5, off, 64);
    p6 += __shfl_xor(p6, off, 64); p7 += __shfl_xor(p7, off, 64);
  }
  if (lane == 0) {
    float* a = s_src + (size_t)n * 4; a[0] = p0; a[1] = p1; a[2] = p2; a[3] = p3;
    float* b = s_dst + (size_t)n * 4; b[0] = p4; b[1] = p5; b[2] = p6; b[3] = p7;
  }
}

// ---------- softmax + input-space aggregation (wave per dst node) ----------
// agg[(n-n0)][h*DIN + c] = sum_e w[e,h] * h_in[src_e][c]   (fp32)
template <int DIN>
__global__ __launch_bounds__(256) void k_attn_agg(const float* __restrict__ hin,
                                                  const int* __restrict__ csr,
                                                  const int* __restrict__ ofs,
                                                  const float* __restrict__ prep,
                                                  const float* __restrict__ s_src,
                                                  const float* __restrict__ s_dst,
                                                  float* __restrict__ agg, int n0) {
  constexpr int ACC = (4 * DIN) / 64;   // 1 / 2 / 8
  __shared__ float se[68];              // 36 used, zero-padded to 64 type-slots
  int tid = threadIdx.x, lane = tid & 63, wv = tid >> 6;
  for (int j = tid; j < 68; j += 256) se[j] = (j < 36) ? prep[1024 + j] : 0.0f;
  __syncthreads();
  int n = n0 + blockIdx.x * 4 + wv;
  int o0 = ofs[n];
  int kd = ofs[n + 1] - o0;
  kd = max(0, min(kd, E_TOT));
  if (o0 < 0) o0 = 0; if (o0 > E_TOT - 1) o0 = E_TOT - 1;
  const float* sdp = s_dst + (size_t)n * 4;
  float sd0 = sdp[0], sd1 = sdp[1], sd2 = sdp[2], sd3 = sdp[3];

  float m0 = -1e30f, m1 = -1e30f, m2 = -1e30f, m3 = -1e30f;
  float z0 = 0, z1 = 0, z2 = 0, z3 = 0;
  for (int i = lane; i < kd; i += 64) {
    int ent = csr[o0 + i];
    int sx = ent & (N_NODES - 1);
    int tt = (ent >> 16) & 15;
    const float4 sv = *reinterpret_cast<const float4*>(s_src + (size_t)sx * 4);
    float a0 = lrelu(sv.x + sd0 + se[tt * 4 + 0]);
    float a1 = lrelu(sv.y + sd1 + se[tt * 4 + 1]);
    float a2 = lrelu(sv.z + sd2 + se[tt * 4 + 2]);
    float a3 = lrelu(sv.w + sd3 + se[tt * 4 + 3]);
    osm_upd(m0, z0, a0); osm_upd(m1, z1, a1); osm_upd(m2, z2, a2); osm_upd(m3, z3, a3);
  }
#pragma unroll
  for (int off = 32; off >= 1; off >>= 1) {
    osm_comb(m0, z0, off); osm_comb(m1, z1, off);
    osm_comb(m2, z2, off); osm_comb(m3, z3, off);
  }
  float r0 = (z0 > 0.0f) ? 1.0f / z0 : 0.0f;
  float r1 = (z1 > 0.0f) ? 1.0f / z1 : 0.0f;
  float r2 = (z2 > 0.0f) ? 1.0f / z2 : 0.0f;
  float r3 = (z3 > 0.0f) ? 1.0f / z3 : 0.0f;

  float acc[ACC];
#pragma unroll
  for (int q = 0; q < ACC; ++q) acc[q] = 0.0f;

  for (int b0 = 0; b0 < kd; b0 += 64) {
    int i = b0 + lane;
    int sx = 0; float w0 = 0, w1 = 0, w2 = 0, w3 = 0;
    if (i < kd) {
      int ent = csr[o0 + i];
      sx = ent & (N_NODES - 1);
      int tt = (ent >> 16) & 15;
      const float4 sv = *reinterpret_cast<const float4*>(s_src + (size_t)sx * 4);
      w0 = __expf(lrelu(sv.x + sd0 + se[tt * 4 + 0]) - m0) * r0;
      w1 = __expf(lrelu(sv.y + sd1 + se[tt * 4 + 1]) - m1) * r1;
      w2 = __expf(lrelu(sv.z + sd2 + se[tt * 4 + 2]) - m2) * r2;
      w3 = __expf(lrelu(sv.w + sd3 + se[tt * 4 + 3]) - m3) * r3;
    }
    int cnt = min(64, kd - b0);
    for (int e = 0; e < cnt; ++e) {
      int se_ = __shfl(sx, e, 64);
      float u0 = __shfl(w0, e, 64), u1 = __shfl(w1, e, 64);
      float u2 = __shfl(w2, e, 64), u3 = __shfl(w3, e, 64);
      const float* row = hin + (size_t)se_ * DIN;
      if constexpr (DIN == 128) {
        float v0 = row[lane];
        float v1 = row[64 + lane];
        acc[0] += u0 * v0; acc[1] += u0 * v1;
        acc[2] += u1 * v0; acc[3] += u1 * v1;
        acc[4] += u2 * v0; acc[5] += u2 * v1;
        acc[6] += u3 * v0; acc[7] += u3 * v1;
      } else if constexpr (DIN == 32) {
        float v = row[lane & 31];
        bool hi = lane >= 32;
        float wa = hi ? u1 : u0;
        float wb = hi ? u3 : u2;
        acc[0] += wa * v; acc[1] += wb * v;
      } else {
        float v = row[lane & 15];
        int hh = lane >> 4;
        float wa = (hh == 0) ? u0 : (hh == 1) ? u1 : (hh == 2) ? u2 : u3;
        acc[0] += wa * v;
      }
    }
  }

  float* ar = agg + (size_t)(n - n0) * (4 * DIN);
  if constexpr (DIN == 128) {
#pragma unroll
    for (int h = 0; h < 4; ++h) {
      ar[h * 128 + lane]      = acc[2 * h];
      ar[h * 128 + 64 + lane] = acc[2 * h + 1];
    }
  } else if constexpr (DIN == 32) {
    ar[lane]      = acc[0];   // (h=lane>>5)*32 + (lane&31) == lane
    ar[64 + lane] = acc[1];
  } else {
    ar[lane] = acc[0];        // (lane>>4)*16 + (lane&15) == lane
  }
}

// ---------- GEMM: out[m0+m][j] = act( 0.25 * sum_k agg[m][k] * Wv[k][j] + b[j] ) ----------
// Wv[k][j] with k = h*DIN+i maps to W[i][h*DOUT+j] (on-the-fly index)
template <int BM, int BN, int BK, int TM, int TN, int NT, int DIN, int DOUT, bool RELU>
__global__ __launch_bounds__(NT) void k_gemm(const float* __restrict__ A,
                                             const float* __restrict__ W,
                                             const float* __restrict__ bias,
                                             float* __restrict__ out, int m0) {
  constexpr int K = 4 * DIN;
  constexpr int LDA = BM + 4;
  constexpr int LDB = BN + 4;
  __shared__ __align__(16) float As[BK * LDA];   // transposed: As[k][m]
  __shared__ __align__(16) float Bs[BK * LDB];
  const int tid = threadIdx.x;
  const int tx = tid % (BN / TN);
  const int ty = tid / (BN / TN);
  const int mb = blockIdx.y * BM;     // chunk-local row base
  const int jb = blockIdx.x * BN;
  float acc[TM][TN] = {};
  constexpr int ITA = (BM * BK) / (NT * 4);
  constexpr int ITB = (BK * BN) / (NT * 4);
  for (int kb = 0; kb < K; kb += BK) {
#pragma unroll
    for (int it = 0; it < ITA; ++it) {
      int f = it * NT * 4 + tid * 4;
      int r = f / BK, c = f % BK;
      float4 u = *reinterpret_cast<const float4*>(A + (size_t)(mb + r) * K + kb + c);
      As[(c + 0) * LDA + r] = u.x;
      As[(c + 1) * LDA + r] = u.y;
      As[(c + 2) * LDA + r] = u.z;
      As[(c + 3) * LDA + r] = u.w;
    }
#pragma unroll
    for (int it = 0; it < ITB; ++it) {
      int f = it * NT * 4 + tid * 4;
      int kk = f / BN, jj = f % BN;
      int k = kb + kk; int h = k / DIN; int i = k % DIN;
      float4 u = *reinterpret_cast<const float4*>(W + (size_t)i * 4 * DOUT + h * DOUT + jb + jj);
      Bs[kk * LDB + jj + 0] = u.x;
      Bs[kk * LDB + jj + 1] = u.y;
      Bs[kk * LDB + jj + 2] = u.z;
      Bs[kk * LDB + jj + 3] = u.w;
    }
    __syncthreads();
#pragma unroll
    for (int kk = 0; kk < BK; ++kk) {
      float a_[TM], b_[TN];
#pragma unroll
      for (int q = 0; q < TM / 4; ++q) {
        float4 v = *reinterpret_cast<const float4*>(&As[kk * LDA + ty * TM + q * 4]);
        a_[q * 4 + 0] = v.x; a_[q * 4 + 1] = v.y; a_[q * 4 + 2] = v.z; a_[q * 4 + 3] = v.w;
      }
#pragma unroll
      for (int q = 0; q < TN / 4; ++q) {
        float4 v = *reinterpret_cast<const float4*>(&Bs[kk * LDB + tx * TN + q * 4]);
        b_[q * 4 + 0] = v.x; b_[q * 4 + 1] = v.y; b_[q * 4 + 2] = v.z; b_[q * 4 + 3] = v.w;
      }
#pragma unroll
      for (int ii = 0; ii < TM; ++ii)
#pragma unroll
        for (int jj = 0; jj < TN; ++jj)
          acc[ii][jj] = fmaf(a_[ii], b_[jj], acc[ii][jj]);
    }
    __syncthreads();
  }
#pragma unroll
  for (int ii = 0; ii < TM; ++ii) {
    int m = mb + ty * TM + ii;
#pragma unroll
    for (int jj = 0; jj < TN; ++jj) {
      int j = jb + tx * TN + jj;
      float v = acc[ii][jj] * 0.25f + bias[j];
      if (RELU) v = fmaxf(v, 0.0f);
      if (!isfinite(v)) v = 0.0f;      // diagnostic guard; no-op when correct
      out[(size_t)(m0 + m) * DOUT + j] = v;
    }
  }
}

// ---------- launch ----------
extern "C" void kernel_launch(void* const* d_in, const int* in_sizes, int n_in,
                              void* d_out, int out_size, void* d_ws, size_t ws_size,
                              hipStream_t stream) {
  (void)in_sizes; (void)n_in; (void)out_size; (void)ws_size;
  const float* x   = (const float*)d_in[0];
  const int*   ei  = (const int*)d_in[1];
  const float* W1  = (const float*)d_in[2];
  const float* We1 = (const float*)d_in[3];
  const float* as1 = (const float*)d_in[4];
  const float* ad1 = (const float*)d_in[5];
  const float* ae1 = (const float*)d_in[6];
  const float* b1  = (const float*)d_in[7];
  const float* W2  = (const float*)d_in[8];
  const float* We2 = (const float*)d_in[9];
  const float* as2 = (const float*)d_in[10];
  const float* ad2 = (const float*)d_in[11];
  const float* ae2 = (const float*)d_in[12];
  const float* b2  = (const float*)d_in[13];
  const float* W3  = (const float*)d_in[14];
  const float* We3 = (const float*)d_in[15];
  const float* as3 = (const float*)d_in[16];
  const float* ad3 = (const float*)d_in[17];
  const float* ae3 = (const float*)d_in[18];
  const float* b3  = (const float*)d_in[19];

  // workspace layout (~38 MB, 256B-aligned offsets)
  char* p = (char*)d_ws;
  int* ofs    = (int*)(p + 0);           // (N+1)*4 -> reserve 131328
  int* deg    = (int*)(p + 131328);      // 131072
  int* cur    = (int*)(p + 262400);      // 131072
  int* csr    = (int*)(p + 393472);      // 655360
  float* ssrc = (float*)(p + 1048832);   // 524288   [N][4]
  float* sdst = (float*)(p + 1573120);   // 524288   [N][4]
  float* prep = (float*)(p + 2097408);   // 4608
  float* h1   = (float*)(p + 2102016);   // 4194304  [N][32]
  float* h2   = (float*)(p + 6296320);   // 16777216 [N][128]
  float* agg  = (float*)(p + 23073536);  // 16777216 max( [N][64], [CH2][128], [CH3][512] )
  // end: 39850752 B

  // ---- CSR by dst (shared by all 3 layers) ----
  hipMemsetAsync(deg, 0, N_NODES * 4, stream);
  k_deg <<<E_TOT / 256, 256, 0, stream>>>(ei, deg);
  k_scan<<<1, 1024, 0, stream>>>(deg, ofs, cur);
  k_fill<<<E_TOT / 256, 256, 0, stream>>>(ei, cur, csr);

  // ---- layer 1: din=16, dout=32 ----  (tasks = 164 waves)
  k_prep<<<(164 * 64 + 255) / 256, 256, 0, stream>>>(W1, We1, as1, ad1, ae1, prep, 16, 32);
  k_scores<16><<<N_NODES / 4, 256, 0, stream>>>(x, prep, ssrc, sdst);
  k_attn_agg<16><<<N_NODES / 4, 256, 0, stream>>>(x, csr, ofs, prep, ssrc, sdst, agg, 0);
  k_gemm<64, 32, 16, 4, 4, 128, 16, 32, true>
      <<<dim3(1, N_NODES / 64), 128, 0, stream>>>(agg, W1, b1, h1, 0);

  // ---- layer 2: din=32, dout=128, chunked ----  (tasks = 292 waves)
  k_prep<<<(292 * 64 + 255) / 256, 256, 0, stream>>>(W2, We2, as2, ad2, ae2, prep, 32, 128);
  k_scores<32><<<N_NODES / 4, 256, 0, stream>>>(h1, prep, ssrc, sdst);
  for (int c0 = 0; c0 < N_NODES; c0 += CH2) {
    k_attn_agg<32><<<CH2 / 4, 256, 0, stream>>>(h1, csr, ofs, prep, ssrc, sdst, agg, c0);
    k_gemm<128, 128, 8, 8, 8, 256, 32, 128, true>
        <<<dim3(1, CH2 / 128), 256, 0, stream>>>(agg, W2, b2, h2, c0);
  }

  // ---- layer 3: din=128, dout=512 (no relu), chunked ----  (tasks = 1060 waves)
  k_prep<<<(1060 * 64 + 255) / 256, 256, 0, stream>>>(W3, We3, as3, ad3, ae3, prep, 128, 512);
  k_scores<128><<<N_NODES / 4, 256, 0, stream>>>(h2, prep, ssrc, sdst);
  for (int c0 = 0; c0 < N_NODES; c0 += CH3) {
    k_attn_agg<128><<<CH3 / 4, 256, 0, stream>>>(h2, csr, ofs, prep, ssrc, sdst, agg, c0);
    k_gemm<128, 128, 8, 8, 8, 256, 128, 512, false>
        <<<dim3(512 / 128, CH3 / 128), 256, 0, stream>>>(agg, W3, b3, (float*)d_out, c0);
  }
}

// Round 6
// 515.898 us; speedup vs baseline: 2.2963x; 1.5417x over previous
//
#include <hip/hip_runtime.h>
#include <hip/hip_bf16.h>
#include <math.h>

// Problem constants (NodeEncoder: 3-layer GAT on chess graph)
#define N_NODES 32768
#define E_PER   16384
#define T_TYPES 8
#define E_TYPED (T_TYPES * E_PER)      // 131072
#define E_TOT   (E_TYPED + N_NODES)    // 163840 (with self loops)
#define NEG_SLOPE 0.2f
#define CH2 16384                       // layer-2 node chunk
#define CH3 8192                        // layer-3 node chunk

typedef _Float16 f16x8 __attribute__((ext_vector_type(8)));
typedef float f32x4 __attribute__((ext_vector_type(4)));

// ---------- helpers ----------
__device__ __forceinline__ float lrelu(float a) { return a > 0.0f ? a : NEG_SLOPE * a; }

__device__ __forceinline__ void osm_upd(float& m, float& z, float a) {
  if (a > m) { z = z * __expf(m - a) + 1.0f; m = a; }
  else       { z += __expf(a - m); }
}
__device__ __forceinline__ void osm_comb(float& m, float& z, int off) {
  float om = __shfl_xor(m, off, 64);
  float oz = __shfl_xor(z, off, 64);
  float nm = fmaxf(m, om);
  z = z * __expf(m - nm) + oz * __expf(om - nm);
  m = nm;
}

// ---------- CSR build (by dst) ----------
__global__ __launch_bounds__(256) void k_deg(const int* __restrict__ ei, int* __restrict__ deg) {
  int e = blockIdx.x * 256 + threadIdx.x;  // grid sized exactly E_TOT/256
  int dst;
  if (e < E_TYPED) { int t = e >> 14; int j = e & (E_PER - 1); dst = ei[(2 * t + 1) * E_PER + j]; }
  else dst = e - E_TYPED;
  atomicAdd(deg + (dst & (N_NODES - 1)), 1);
}

// exclusive scan of 32768 counts, one 1024-thread block (32/thread).
// deg / ofs / cur are DISTINCT buffers (no aliasing).
__global__ __launch_bounds__(1024) void k_scan(const int* deg, int* ofs, int* cur) {
  __shared__ int part[1024];
  int tid = threadIdx.x;
  int base = tid * 32;
  int loc[32];
  int run = 0;
#pragma unroll
  for (int j = 0; j < 32; ++j) { loc[j] = run; run += deg[base + j]; }
  part[tid] = run;
  int self = run;
  __syncthreads();
  for (int off = 1; off < 1024; off <<= 1) {
    int v = (tid >= off) ? part[tid - off] : 0;
    __syncthreads();
    part[tid] += v;
    __syncthreads();
  }
  int excl = part[tid] - self;
#pragma unroll
  for (int j = 0; j < 32; ++j) { int v = excl + loc[j]; ofs[base + j] = v; cur[base + j] = v; }
  if (tid == 1023) ofs[N_NODES] = part[1023];
}

__global__ __launch_bounds__(256) void k_fill(const int* __restrict__ ei, int* __restrict__ cur,
                                              int* __restrict__ csr) {
  int e = blockIdx.x * 256 + threadIdx.x;
  int src, dst, t;
  if (e < E_TYPED) { t = e >> 14; int j = e & (E_PER - 1); src = ei[2 * t * E_PER + j]; dst = ei[(2 * t + 1) * E_PER + j]; }
  else { src = dst = e - E_TYPED; t = 8; }
  int pos = atomicAdd(cur + (dst & (N_NODES - 1)), 1);
  if (pos >= 0 && pos < E_TOT)
    csr[pos] = (src & (N_NODES - 1)) | (t << 16);
}

// ---------- per-layer folded attention vectors (one wave per output) ----------
// prep layout (floats): [0..511] v_src[h*128+i], [512..1023] v_dst[h*128+i],
//                       [1024..1059] s_edge[t*4+h], t=0..8 (8 = self loop)
__global__ __launch_bounds__(256) void k_prep(const float* __restrict__ W,
                                              const float* __restrict__ We,
                                              const float* __restrict__ asrc,
                                              const float* __restrict__ adst,
                                              const float* __restrict__ aedge,
                                              float* __restrict__ prep,
                                              int din, int dout) {
  int task = (blockIdx.x * 256 + threadIdx.x) >> 6;
  int lane = threadIdx.x & 63;
  int hd = 4 * din;
  float s = 0.0f;
  if (task < 2 * hd) {
    int k = (task < hd) ? task : task - hd;
    int h = k / din, i = k % din;
    const float* a = (task < hd) ? asrc : adst;
    for (int c = lane; c < dout; c += 64)
      s += W[(size_t)i * 4 * dout + h * dout + c] * a[h * dout + c];
#pragma unroll
    for (int off = 32; off >= 1; off >>= 1) s += __shfl_xor(s, off, 64);
    if (lane == 0) prep[((task < hd) ? 0 : 512) + h * 128 + i] = s;
  } else if (task < 2 * hd + 32) {
    int k = task - 2 * hd; int t = k >> 2, h = k & 3;
    for (int c = lane; c < dout; c += 64)
      s += We[(size_t)t * 4 * dout + h * dout + c] * aedge[h * dout + c];
#pragma unroll
    for (int off = 32; off >= 1; off >>= 1) s += __shfl_xor(s, off, 64);
    if (lane == 0) prep[1024 + t * 4 + h] = s;
  } else if (task < 2 * hd + 36) {
    int h = task - 2 * hd - 32;
    for (int t = 0; t < 8; ++t)
      for (int c = lane; c < dout; c += 64)
        s += We[(size_t)t * 4 * dout + h * dout + c] * aedge[h * dout + c];
#pragma unroll
    for (int off = 32; off >= 1; off >>= 1) s += __shfl_xor(s, off, 64);
    if (lane == 0) prep[1024 + 32 + h] = s * 0.125f;   // loop edge attr = mean one-hot
  }
}

// ---------- W3 -> Bt[j][k] fp16 (k = h*128+i), tiled transpose ----------
__global__ __launch_bounds__(256) void k_w3t(const float* __restrict__ W,
                                             _Float16* __restrict__ Bt) {
  __shared__ float T[64][65];
  int jb = blockIdx.x * 64;
  int kb = blockIdx.y * 64;
  int tx = threadIdx.x & 63, ty4 = threadIdx.x >> 6;
  for (int r0 = 0; r0 < 64; r0 += 4) {
    int r = r0 + ty4;
    int k = kb + r, h = k >> 7, i = k & 127;
    T[r][tx] = W[(size_t)i * 2048 + h * 512 + jb + tx];   // coalesced in j
  }
  __syncthreads();
  for (int r0 = 0; r0 < 64; r0 += 4) {
    int r = r0 + ty4;                                     // local j
    Bt[(size_t)(jb + r) * 512 + kb + tx] = (_Float16)T[tx][r];  // coalesced in k
  }
}

// ---------- per-node scores: s_src[n][h], s_dst[n][h] (wave per node) ----------
template <int DIN>
__global__ __launch_bounds__(256) void k_scores(const float* __restrict__ hin,
                                                const float* __restrict__ prep,
                                                float* __restrict__ s_src,
                                                float* __restrict__ s_dst) {
  __shared__ float vv[8 * DIN];
  int tid = threadIdx.x;
  for (int j = tid; j < 8 * DIN; j += 256) {
    int s = j / DIN, i = j % DIN;
    vv[j] = prep[(s & 3) * 128 + i + ((s >= 4) ? 512 : 0)];
  }
  __syncthreads();
  int lane = tid & 63, wv = tid >> 6;
  int n = blockIdx.x * 4 + wv;
  const float* row = hin + (size_t)n * DIN;
  float p0 = 0, p1 = 0, p2 = 0, p3 = 0, p4 = 0, p5 = 0, p6 = 0, p7 = 0;
  for (int c = lane; c < DIN; c += 64) {
    float v = row[c];
    p0 += v * vv[0 * DIN + c]; p1 += v * vv[1 * DIN + c];
    p2 += v * vv[2 * DIN + c]; p3 += v * vv[3 * DIN + c];
    p4 += v * vv[4 * DIN + c]; p5 += v * vv[5 * DIN + c];
    p6 += v * vv[6 * DIN + c]; p7 += v * vv[7 * DIN + c];
  }
#pragma unroll
  for (int off = 32; off >= 1; off >>= 1) {
    p0 += __shfl_xor(p0, off, 64); p1 += __shfl_xor(p1, off, 64);
    p2 += __shfl_xor(p2, off, 64); p3 += __shfl_xor(p3, off, 64);
    p4 += __shfl_xor(p4, off, 64); p5 += __shfl_xor(p5, off, 64);
    p6 += __shfl_xor(p6, off, 64); p7 += __shfl_xor(p7, off, 64);
  }
  if (lane == 0) {
    float* a = s_src + (size_t)n * 4; a[0] = p0; a[1] = p1; a[2] = p2; a[3] = p3;
    float* b = s_dst + (size_t)n * 4; b[0] = p4; b[1] = p5; b[2] = p6; b[3] = p7;
  }
}

// ---------- softmax + input-space aggregation (wave per dst node) ----------
// agg[(n-n0)][h*DIN + c] = sum_e w[e,h] * h_in[src_e][c]   (stored as TO)
template <int DIN, typename TO>
__global__ __launch_bounds__(256) void k_attn_agg(const float* __restrict__ hin,
                                                  const int* __restrict__ csr,
                                                  const int* __restrict__ ofs,
                                                  const float* __restrict__ prep,
                                                  const float* __restrict__ s_src,
                                                  const float* __restrict__ s_dst,
                                                  TO* __restrict__ agg, int n0) {
  constexpr int ACC = (4 * DIN) / 64;   // 1 / 2 / 8
  __shared__ float se[68];              // 36 used, zero-padded to 64 type-slots
  int tid = threadIdx.x, lane = tid & 63, wv = tid >> 6;
  for (int j = tid; j < 68; j += 256) se[j] = (j < 36) ? prep[1024 + j] : 0.0f;
  __syncthreads();
  int n = n0 + blockIdx.x * 4 + wv;
  int o0 = ofs[n];
  int kd = ofs[n + 1] - o0;
  kd = max(0, min(kd, E_TOT));
  if (o0 < 0) o0 = 0; if (o0 > E_TOT - 1) o0 = E_TOT - 1;
  const float* sdp = s_dst + (size_t)n * 4;
  float sd0 = sdp[0], sd1 = sdp[1], sd2 = sdp[2], sd3 = sdp[3];

  float m0 = -1e30f, m1 = -1e30f, m2 = -1e30f, m3 = -1e30f;
  float z0 = 0, z1 = 0, z2 = 0, z3 = 0;
  for (int i = lane; i < kd; i += 64) {
    int ent = csr[o0 + i];
    int sx = ent & (N_NODES - 1);
    int tt = (ent >> 16) & 15;
    const float4 sv = *reinterpret_cast<const float4*>(s_src + (size_t)sx * 4);
    float a0 = lrelu(sv.x + sd0 + se[tt * 4 + 0]);
    float a1 = lrelu(sv.y + sd1 + se[tt * 4 + 1]);
    float a2 = lrelu(sv.z + sd2 + se[tt * 4 + 2]);
    float a3 = lrelu(sv.w + sd3 + se[tt * 4 + 3]);
    osm_upd(m0, z0, a0); osm_upd(m1, z1, a1); osm_upd(m2, z2, a2); osm_upd(m3, z3, a3);
  }
#pragma unroll
  for (int off = 32; off >= 1; off >>= 1) {
    osm_comb(m0, z0, off); osm_comb(m1, z1, off);
    osm_comb(m2, z2, off); osm_comb(m3, z3, off);
  }
  float r0 = (z0 > 0.0f) ? 1.0f / z0 : 0.0f;
  float r1 = (z1 > 0.0f) ? 1.0f / z1 : 0.0f;
  float r2 = (z2 > 0.0f) ? 1.0f / z2 : 0.0f;
  float r3 = (z3 > 0.0f) ? 1.0f / z3 : 0.0f;

  float acc[ACC];
#pragma unroll
  for (int q = 0; q < ACC; ++q) acc[q] = 0.0f;

  for (int b0 = 0; b0 < kd; b0 += 64) {
    int i = b0 + lane;
    int sx = 0; float w0 = 0, w1 = 0, w2 = 0, w3 = 0;
    if (i < kd) {
      int ent = csr[o0 + i];
      sx = ent & (N_NODES - 1);
      int tt = (ent >> 16) & 15;
      const float4 sv = *reinterpret_cast<const float4*>(s_src + (size_t)sx * 4);
      w0 = __expf(lrelu(sv.x + sd0 + se[tt * 4 + 0]) - m0) * r0;
      w1 = __expf(lrelu(sv.y + sd1 + se[tt * 4 + 1]) - m1) * r1;
      w2 = __expf(lrelu(sv.z + sd2 + se[tt * 4 + 2]) - m2) * r2;
      w3 = __expf(lrelu(sv.w + sd3 + se[tt * 4 + 3]) - m3) * r3;
    }
    int cnt = min(64, kd - b0);
    for (int e = 0; e < cnt; ++e) {
      int se_ = __shfl(sx, e, 64);
      float u0 = __shfl(w0, e, 64), u1 = __shfl(w1, e, 64);
      float u2 = __shfl(w2, e, 64), u3 = __shfl(w3, e, 64);
      const float* row = hin + (size_t)se_ * DIN;
      if constexpr (DIN == 128) {
        float v0 = row[lane];
        float v1 = row[64 + lane];
        acc[0] += u0 * v0; acc[1] += u0 * v1;
        acc[2] += u1 * v0; acc[3] += u1 * v1;
        acc[4] += u2 * v0; acc[5] += u2 * v1;
        acc[6] += u3 * v0; acc[7] += u3 * v1;
      } else if constexpr (DIN == 32) {
        float v = row[lane & 31];
        bool hi = lane >= 32;
        float wa = hi ? u1 : u0;
        float wb = hi ? u3 : u2;
        acc[0] += wa * v; acc[1] += wb * v;
      } else {
        float v = row[lane & 15];
        int hh = lane >> 4;
        float wa = (hh == 0) ? u0 : (hh == 1) ? u1 : (hh == 2) ? u2 : u3;
        acc[0] += wa * v;
      }
    }
  }

  TO* ar = agg + (size_t)(n - n0) * (4 * DIN);
  if constexpr (DIN == 128) {
#pragma unroll
    for (int h = 0; h < 4; ++h) {
      ar[h * 128 + lane]      = (TO)acc[2 * h];
      ar[h * 128 + 64 + lane] = (TO)acc[2 * h + 1];
    }
  } else if constexpr (DIN == 32) {
    ar[lane]      = (TO)acc[0];   // (h=lane>>5)*32 + (lane&31) == lane
    ar[64 + lane] = (TO)acc[1];
  } else {
    ar[lane] = (TO)acc[0];        // (lane>>4)*16 + (lane&15) == lane
  }
}

// ---------- fp32 GEMM (layers 1-2) ----------
template <int BM, int BN, int BK, int TM, int TN, int NT, int DIN, int DOUT, bool RELU>
__global__ __launch_bounds__(NT) void k_gemm(const float* __restrict__ A,
                                             const float* __restrict__ W,
                                             const float* __restrict__ bias,
                                             float* __restrict__ out, int m0) {
  constexpr int K = 4 * DIN;
  constexpr int LDA = BM + 4;
  constexpr int LDB = BN + 4;
  __shared__ __align__(16) float As[BK * LDA];   // transposed: As[k][m]
  __shared__ __align__(16) float Bs[BK * LDB];
  const int tid = threadIdx.x;
  const int tx = tid % (BN / TN);
  const int ty = tid / (BN / TN);
  const int mb = blockIdx.y * BM;     // chunk-local row base
  const int jb = blockIdx.x * BN;
  float acc[TM][TN] = {};
  constexpr int ITA = (BM * BK) / (NT * 4);
  constexpr int ITB = (BK * BN) / (NT * 4);
  for (int kb = 0; kb < K; kb += BK) {
#pragma unroll
    for (int it = 0; it < ITA; ++it) {
      int f = it * NT * 4 + tid * 4;
      int r = f / BK, c = f % BK;
      float4 u = *reinterpret_cast<const float4*>(A + (size_t)(mb + r) * K + kb + c);
      As[(c + 0) * LDA + r] = u.x;
      As[(c + 1) * LDA + r] = u.y;
      As[(c + 2) * LDA + r] = u.z;
      As[(c + 3) * LDA + r] = u.w;
    }
#pragma unroll
    for (int it = 0; it < ITB; ++it) {
      int f = it * NT * 4 + tid * 4;
      int kk = f / BN, jj = f % BN;
      int k = kb + kk; int h = k / DIN; int i = k % DIN;
      float4 u = *reinterpret_cast<const float4*>(W + (size_t)i * 4 * DOUT + h * DOUT + jb + jj);
      Bs[kk * LDB + jj + 0] = u.x;
      Bs[kk * LDB + jj + 1] = u.y;
      Bs[kk * LDB + jj + 2] = u.z;
      Bs[kk * LDB + jj + 3] = u.w;
    }
    __syncthreads();
#pragma unroll
    for (int kk = 0; kk < BK; ++kk) {
      float a_[TM], b_[TN];
#pragma unroll
      for (int q = 0; q < TM / 4; ++q) {
        float4 v = *reinterpret_cast<const float4*>(&As[kk * LDA + ty * TM + q * 4]);
        a_[q * 4 + 0] = v.x; a_[q * 4 + 1] = v.y; a_[q * 4 + 2] = v.z; a_[q * 4 + 3] = v.w;
      }
#pragma unroll
      for (int q = 0; q < TN / 4; ++q) {
        float4 v = *reinterpret_cast<const float4*>(&Bs[kk * LDB + tx * TN + q * 4]);
        b_[q * 4 + 0] = v.x; b_[q * 4 + 1] = v.y; b_[q * 4 + 2] = v.z; b_[q * 4 + 3] = v.w;
      }
#pragma unroll
      for (int ii = 0; ii < TM; ++ii)
#pragma unroll
        for (int jj = 0; jj < TN; ++jj)
          acc[ii][jj] = fmaf(a_[ii], b_[jj], acc[ii][jj]);
    }
    __syncthreads();
  }
#pragma unroll
  for (int ii = 0; ii < TM; ++ii) {
    int m = mb + ty * TM + ii;
#pragma unroll
    for (int jj = 0; jj < TN; ++jj) {
      int j = jb + tx * TN + jj;
      float v = acc[ii][jj] * 0.25f + bias[j];
      if (RELU) v = fmaxf(v, 0.0f);
      if (!isfinite(v)) v = 0.0f;      // diagnostic guard; no-op when correct
      out[(size_t)(m0 + m) * DOUT + j] = v;
    }
  }
}

// ---------- fp16 MFMA GEMM (layer 3): out = 0.25*A@Bt^T + bias ----------
// A[m][k] fp16 (chunk rows), Bt[j][k] fp16; K=512, DOUT=512.
// Frag layouts (m120/m92-verified): A[m=lane&15][k=quad*8+j]; B mirrors with
// n=lane&15; C/D col=lane&15, row=quad*4+reg.
__global__ __launch_bounds__(256) void k_gemm_mfma(const _Float16* __restrict__ A,
                                                   const _Float16* __restrict__ Bt,
                                                   const float* __restrict__ bias,
                                                   float* __restrict__ out, int m0) {
  constexpr int K = 512, DOUT = 512, BM = 128, BK = 32;
  constexpr int LD = BK + 8;                 // 40 halves: <=2-way banks (free)
  __shared__ _Float16 As[BM * LD];           // 10 KB
  __shared__ _Float16 Bs[BM * LD];           // 10 KB
  const int tid = threadIdx.x;
  const int lane = tid & 63, wv = tid >> 6;
  const int quad = lane >> 4, l16 = lane & 15;
  const int wm = (wv >> 1) * 64, wn = (wv & 1) * 64;
  const int mb = blockIdx.y * BM, jb = blockIdx.x * BM;

  f32x4 acc[4][4] = {};
  float bv[4];
#pragma unroll
  for (int fj = 0; fj < 4; ++fj) bv[fj] = bias[jb + wn + fj * 16 + l16];

  for (int kb = 0; kb < K; kb += BK) {
    __syncthreads();
#pragma unroll
    for (int it = 0; it < 2; ++it) {       // 512 x 16B loads each matrix
      int idx = it * 256 + tid;
      int r = idx >> 2, cq = (idx & 3) * 8;
      *reinterpret_cast<f16x8*>(&As[r * LD + cq]) =
          *reinterpret_cast<const f16x8*>(A + (size_t)(mb + r) * K + kb + cq);
      *reinterpret_cast<f16x8*>(&Bs[r * LD + cq]) =
          *reinterpret_cast<const f16x8*>(Bt + (size_t)(jb + r) * K + kb + cq);
    }
    __syncthreads();
    f16x8 af[4], bf[4];
#pragma unroll
    for (int f = 0; f < 4; ++f) {
      af[f] = *reinterpret_cast<const f16x8*>(&As[(wm + f * 16 + l16) * LD + quad * 8]);
      bf[f] = *reinterpret_cast<const f16x8*>(&Bs[(wn + f * 16 + l16) * LD + quad * 8]);
    }
#pragma unroll
    for (int fi = 0; fi < 4; ++fi)
#pragma unroll
      for (int fj = 0; fj < 4; ++fj)
        acc[fi][fj] = __builtin_amdgcn_mfma_f32_16x16x32_f16(af[fi], bf[fj], acc[fi][fj], 0, 0, 0);
  }
#pragma unroll
  for (int fi = 0; fi < 4; ++fi)
#pragma unroll
    for (int reg = 0; reg < 4; ++reg) {
      int m = mb + wm + fi * 16 + quad * 4 + reg;
#pragma unroll
      for (int fj = 0; fj < 4; ++fj) {
        int j = jb + wn + fj * 16 + l16;
        float v = acc[fi][fj][reg] * 0.25f + bv[fj];
        if (!isfinite(v)) v = 0.0f;
        out[(size_t)(m0 + m) * DOUT + j] = v;
      }
    }
}

// ---------- launch ----------
extern "C" void kernel_launch(void* const* d_in, const int* in_sizes, int n_in,
                              void* d_out, int out_size, void* d_ws, size_t ws_size,
                              hipStream_t stream) {
  (void)in_sizes; (void)n_in; (void)out_size; (void)ws_size;
  const float* x   = (const float*)d_in[0];
  const int*   ei  = (const int*)d_in[1];
  const float* W1  = (const float*)d_in[2];
  const float* We1 = (const float*)d_in[3];
  const float* as1 = (const float*)d_in[4];
  const float* ad1 = (const float*)d_in[5];
  const float* ae1 = (const float*)d_in[6];
  const float* b1  = (const float*)d_in[7];
  const float* W2  = (const float*)d_in[8];
  const float* We2 = (const float*)d_in[9];
  const float* as2 = (const float*)d_in[10];
  const float* ad2 = (const float*)d_in[11];
  const float* ae2 = (const float*)d_in[12];
  const float* b2  = (const float*)d_in[13];
  const float* W3  = (const float*)d_in[14];
  const float* We3 = (const float*)d_in[15];
  const float* as3 = (const float*)d_in[16];
  const float* ad3 = (const float*)d_in[17];
  const float* ae3 = (const float*)d_in[18];
  const float* b3  = (const float*)d_in[19];

  // workspace layout (~32 MB, 256B-aligned offsets)
  char* p = (char*)d_ws;
  int* ofs    = (int*)(p + 0);           // (N+1)*4 -> reserve 131328
  int* deg    = (int*)(p + 131328);      // 131072
  int* cur    = (int*)(p + 262400);      // 131072
  int* csr    = (int*)(p + 393472);      // 655360
  float* ssrc = (float*)(p + 1048832);   // 524288   [N][4]
  float* sdst = (float*)(p + 1573120);   // 524288   [N][4]
  float* prep = (float*)(p + 2097408);   // 4608
  float* h1   = (float*)(p + 2102016);   // 4194304  [N][32]
  float* h2   = (float*)(p + 6296320);   // 16777216 [N][128]
  float* agg  = (float*)(p + 23073536);  // 8388608  l1:[N][64]f32 / l2:[CH2][128]f32 / l3:[CH3][512]f16
  _Float16* aggh = (_Float16*)agg;
  _Float16* w3t  = (_Float16*)(p + 31462144);  // 524288  Bt[512][512] fp16
  // end: 31986432 B

  // ---- CSR by dst (shared by all 3 layers) ----
  hipMemsetAsync(deg, 0, N_NODES * 4, stream);
  k_deg <<<E_TOT / 256, 256, 0, stream>>>(ei, deg);
  k_scan<<<1, 1024, 0, stream>>>(deg, ofs, cur);
  k_fill<<<E_TOT / 256, 256, 0, stream>>>(ei, cur, csr);

  // ---- layer 1: din=16, dout=32 ----
  k_prep<<<(164 * 64 + 255) / 256, 256, 0, stream>>>(W1, We1, as1, ad1, ae1, prep, 16, 32);
  k_scores<16><<<N_NODES / 4, 256, 0, stream>>>(x, prep, ssrc, sdst);
  k_attn_agg<16, float><<<N_NODES / 4, 256, 0, stream>>>(x, csr, ofs, prep, ssrc, sdst, agg, 0);
  k_gemm<64, 32, 16, 4, 4, 128, 16, 32, true>
      <<<dim3(1, N_NODES / 64), 128, 0, stream>>>(agg, W1, b1, h1, 0);

  // ---- layer 2: din=32, dout=128, chunked ----
  k_prep<<<(292 * 64 + 255) / 256, 256, 0, stream>>>(W2, We2, as2, ad2, ae2, prep, 32, 128);
  k_scores<32><<<N_NODES / 4, 256, 0, stream>>>(h1, prep, ssrc, sdst);
  for (int c0 = 0; c0 < N_NODES; c0 += CH2) {
    k_attn_agg<32, float><<<CH2 / 4, 256, 0, stream>>>(h1, csr, ofs, prep, ssrc, sdst, agg, c0);
    k_gemm<128, 128, 8, 8, 8, 256, 32, 128, true>
        <<<dim3(1, CH2 / 128), 256, 0, stream>>>(agg, W2, b2, h2, c0);
  }

  // ---- layer 3: din=128, dout=512 (no relu), fp16 MFMA, chunked ----
  k_prep<<<(1060 * 64 + 255) / 256, 256, 0, stream>>>(W3, We3, as3, ad3, ae3, prep, 128, 512);
  k_w3t<<<dim3(8, 8), 256, 0, stream>>>(W3, w3t);
  k_scores<128><<<N_NODES / 4, 256, 0, stream>>>(h2, prep, ssrc, sdst);
  for (int c0 = 0; c0 < N_NODES; c0 += CH3) {
    k_attn_agg<128, _Float16><<<CH3 / 4, 256, 0, stream>>>(h2, csr, ofs, prep, ssrc, sdst, aggh, c0);
    k_gemm_mfma<<<dim3(512 / 128, CH3 / 128), 256, 0, stream>>>(aggh, w3t, b3, (float*)d_out, c0);
  }
}

// Round 7
// 415.017 us; speedup vs baseline: 2.8544x; 1.2431x over previous
//
#include <hip/hip_runtime.h>
#include <hip/hip_bf16.h>
#include <math.h>

// Problem constants (NodeEncoder: 3-layer GAT on chess graph)
#define N_NODES 32768
#define E_PER   16384
#define T_TYPES 8
#define E_TYPED (T_TYPES * E_PER)      // 131072
#define E_TOT   (E_TYPED + N_NODES)    // 163840 (with self loops)
#define NEG_SLOPE 0.2f

typedef _Float16 f16x8 __attribute__((ext_vector_type(8)));
typedef float f32x4 __attribute__((ext_vector_type(4)));

// ---------- helpers ----------
__device__ __forceinline__ float tof(float v) { return v; }
__device__ __forceinline__ float tof(_Float16 v) { return (float)v; }
__device__ __forceinline__ float lrelu(float a) { return a > 0.0f ? a : NEG_SLOPE * a; }

__device__ __forceinline__ void osm_upd(float& m, float& z, float a) {
  if (a > m) { z = z * __expf(m - a) + 1.0f; m = a; }
  else       { z += __expf(a - m); }
}
__device__ __forceinline__ void osm_comb(float& m, float& z, int off) {
  float om = __shfl_xor(m, off, 64);
  float oz = __shfl_xor(z, off, 64);
  float nm = fmaxf(m, om);
  z = z * __expf(m - nm) + oz * __expf(om - nm);
  m = nm;
}

// ---------- CSR build (by dst) ----------
__global__ __launch_bounds__(256) void k_deg(const int* __restrict__ ei, int* __restrict__ deg) {
  int e = blockIdx.x * 256 + threadIdx.x;  // grid sized exactly E_TOT/256
  int dst;
  if (e < E_TYPED) { int t = e >> 14; int j = e & (E_PER - 1); dst = ei[(2 * t + 1) * E_PER + j]; }
  else dst = e - E_TYPED;
  atomicAdd(deg + (dst & (N_NODES - 1)), 1);
}

// exclusive scan of 32768 counts, one 1024-thread block (32/thread).
// deg / ofs / cur are DISTINCT buffers (no aliasing).
__global__ __launch_bounds__(1024) void k_scan(const int* deg, int* ofs, int* cur) {
  __shared__ int part[1024];
  int tid = threadIdx.x;
  int base = tid * 32;
  int loc[32];
  int run = 0;
#pragma unroll
  for (int j = 0; j < 32; ++j) { loc[j] = run; run += deg[base + j]; }
  part[tid] = run;
  int self = run;
  __syncthreads();
  for (int off = 1; off < 1024; off <<= 1) {
    int v = (tid >= off) ? part[tid - off] : 0;
    __syncthreads();
    part[tid] += v;
    __syncthreads();
  }
  int excl = part[tid] - self;
#pragma unroll
  for (int j = 0; j < 32; ++j) { int v = excl + loc[j]; ofs[base + j] = v; cur[base + j] = v; }
  if (tid == 1023) ofs[N_NODES] = part[1023];
}

__global__ __launch_bounds__(256) void k_fill(const int* __restrict__ ei, int* __restrict__ cur,
                                              int* __restrict__ csr) {
  int e = blockIdx.x * 256 + threadIdx.x;
  int src, dst, t;
  if (e < E_TYPED) { t = e >> 14; int j = e & (E_PER - 1); src = ei[2 * t * E_PER + j]; dst = ei[(2 * t + 1) * E_PER + j]; }
  else { src = dst = e - E_TYPED; t = 8; }
  int pos = atomicAdd(cur + (dst & (N_NODES - 1)), 1);
  if (pos >= 0 && pos < E_TOT)
    csr[pos] = (src & (N_NODES - 1)) | (t << 16);
}

// ---------- per-layer folded attention vectors (one wave per output) ----------
// prep layout (floats): [0..511] v_src[h*128+i], [512..1023] v_dst[h*128+i],
//                       [1024..1059] s_edge[t*4+h], t=0..8 (8 = self loop)
__global__ __launch_bounds__(256) void k_prep(const float* __restrict__ W,
                                              const float* __restrict__ We,
                                              const float* __restrict__ asrc,
                                              const float* __restrict__ adst,
                                              const float* __restrict__ aedge,
                                              float* __restrict__ prep,
                                              int din, int dout) {
  int task = (blockIdx.x * 256 + threadIdx.x) >> 6;
  int lane = threadIdx.x & 63;
  int hd = 4 * din;
  float s = 0.0f;
  if (task < 2 * hd) {
    int k = (task < hd) ? task : task - hd;
    int h = k / din, i = k % din;
    const float* a = (task < hd) ? asrc : adst;
    for (int c = lane; c < dout; c += 64)
      s += W[(size_t)i * 4 * dout + h * dout + c] * a[h * dout + c];
#pragma unroll
    for (int off = 32; off >= 1; off >>= 1) s += __shfl_xor(s, off, 64);
    if (lane == 0) prep[((task < hd) ? 0 : 512) + h * 128 + i] = s;
  } else if (task < 2 * hd + 32) {
    int k = task - 2 * hd; int t = k >> 2, h = k & 3;
    for (int c = lane; c < dout; c += 64)
      s += We[(size_t)t * 4 * dout + h * dout + c] * aedge[h * dout + c];
#pragma unroll
    for (int off = 32; off >= 1; off >>= 1) s += __shfl_xor(s, off, 64);
    if (lane == 0) prep[1024 + t * 4 + h] = s;
  } else if (task < 2 * hd + 36) {
    int h = task - 2 * hd - 32;
    for (int t = 0; t < 8; ++t)
      for (int c = lane; c < dout; c += 64)
        s += We[(size_t)t * 4 * dout + h * dout + c] * aedge[h * dout + c];
#pragma unroll
    for (int off = 32; off >= 1; off >>= 1) s += __shfl_xor(s, off, 64);
    if (lane == 0) prep[1024 + 32 + h] = s * 0.125f;   // loop edge attr = mean one-hot
  }
}

// ---------- W -> Bt[j][k] fp16 (k = h*din+i), tiled 64x64 transpose ----------
__global__ __launch_bounds__(256) void k_wt(const float* __restrict__ W,
                                            _Float16* __restrict__ Bt,
                                            int din, int dout) {
  __shared__ float T[64][65];
  int jb = blockIdx.x * 64;
  int kb = blockIdx.y * 64;
  int KK = 4 * din;
  int tx = threadIdx.x & 63, ty4 = threadIdx.x >> 6;
  for (int r0 = 0; r0 < 64; r0 += 4) {
    int r = r0 + ty4;
    int k = kb + r, h = k / din, i = k % din;
    T[r][tx] = W[(size_t)i * 4 * dout + h * dout + jb + tx];    // coalesced in j
  }
  __syncthreads();
  for (int r0 = 0; r0 < 64; r0 += 4) {
    int r = r0 + ty4;                                           // local j
    Bt[(size_t)(jb + r) * KK + kb + tx] = (_Float16)T[tx][r];   // coalesced in k
  }
}

// ---------- per-node scores: s_src[n][h], s_dst[n][h] (wave per node) ----------
template <typename TI, int DIN>
__global__ __launch_bounds__(256) void k_scores(const TI* __restrict__ hin,
                                                const float* __restrict__ prep,
                                                float* __restrict__ s_src,
                                                float* __restrict__ s_dst) {
  __shared__ float vv[8 * DIN];
  int tid = threadIdx.x;
  for (int j = tid; j < 8 * DIN; j += 256) {
    int s = j / DIN, i = j % DIN;
    vv[j] = prep[(s & 3) * 128 + i + ((s >= 4) ? 512 : 0)];
  }
  __syncthreads();
  int lane = tid & 63, wv = tid >> 6;
  int n = blockIdx.x * 4 + wv;
  const TI* row = hin + (size_t)n * DIN;
  float p0 = 0, p1 = 0, p2 = 0, p3 = 0, p4 = 0, p5 = 0, p6 = 0, p7 = 0;
  for (int c = lane; c < DIN; c += 64) {
    float v = tof(row[c]);
    p0 += v * vv[0 * DIN + c]; p1 += v * vv[1 * DIN + c];
    p2 += v * vv[2 * DIN + c]; p3 += v * vv[3 * DIN + c];
    p4 += v * vv[4 * DIN + c]; p5 += v * vv[5 * DIN + c];
    p6 += v * vv[6 * DIN + c]; p7 += v * vv[7 * DIN + c];
  }
#pragma unroll
  for (int off = 32; off >= 1; off >>= 1) {
    p0 += __shfl_xor(p0, off, 64); p1 += __shfl_xor(p1, off, 64);
    p2 += __shfl_xor(p2, off, 64); p3 += __shfl_xor(p3, off, 64);
    p4 += __shfl_xor(p4, off, 64); p5 += __shfl_xor(p5, off, 64);
    p6 += __shfl_xor(p6, off, 64); p7 += __shfl_xor(p7, off, 64);
  }
  if (lane == 0) {
    float* a = s_src + (size_t)n * 4; a[0] = p0; a[1] = p1; a[2] = p2; a[3] = p3;
    float* b = s_dst + (size_t)n * 4; b[0] = p4; b[1] = p5; b[2] = p6; b[3] = p7;
  }
}

// ---------- softmax + input-space aggregation (wave per dst node) ----------
// agg[n][h*DIN + c] = sum_e w[e,h] * h_in[src_e][c]   (stored as TO)
template <typename TI, int DIN, typename TO>
__global__ __launch_bounds__(256) void k_attn_agg(const TI* __restrict__ hin,
                                                  const int* __restrict__ csr,
                                                  const int* __restrict__ ofs,
                                                  const float* __restrict__ prep,
                                                  const float* __restrict__ s_src,
                                                  const float* __restrict__ s_dst,
                                                  TO* __restrict__ agg) {
  constexpr int ACC = (4 * DIN) / 64;   // 1 / 2 / 8
  __shared__ float se[68];              // 36 used, zero-padded to 64 type-slots
  int tid = threadIdx.x, lane = tid & 63, wv = tid >> 6;
  for (int j = tid; j < 68; j += 256) se[j] = (j < 36) ? prep[1024 + j] : 0.0f;
  __syncthreads();
  int n = blockIdx.x * 4 + wv;
  int o0 = ofs[n];
  int kd = ofs[n + 1] - o0;
  kd = max(0, min(kd, E_TOT));
  if (o0 < 0) o0 = 0; if (o0 > E_TOT - 1) o0 = E_TOT - 1;
  const float* sdp = s_dst + (size_t)n * 4;
  float sd0 = sdp[0], sd1 = sdp[1], sd2 = sdp[2], sd3 = sdp[3];

  float m0 = -1e30f, m1 = -1e30f, m2 = -1e30f, m3 = -1e30f;
  float z0 = 0, z1 = 0, z2 = 0, z3 = 0;
  for (int i = lane; i < kd; i += 64) {
    int ent = csr[o0 + i];
    int sx = ent & (N_NODES - 1);
    int tt = (ent >> 16) & 15;
    const float4 sv = *reinterpret_cast<const float4*>(s_src + (size_t)sx * 4);
    float a0 = lrelu(sv.x + sd0 + se[tt * 4 + 0]);
    float a1 = lrelu(sv.y + sd1 + se[tt * 4 + 1]);
    float a2 = lrelu(sv.z + sd2 + se[tt * 4 + 2]);
    float a3 = lrelu(sv.w + sd3 + se[tt * 4 + 3]);
    osm_upd(m0, z0, a0); osm_upd(m1, z1, a1); osm_upd(m2, z2, a2); osm_upd(m3, z3, a3);
  }
#pragma unroll
  for (int off = 32; off >= 1; off >>= 1) {
    osm_comb(m0, z0, off); osm_comb(m1, z1, off);
    osm_comb(m2, z2, off); osm_comb(m3, z3, off);
  }
  float r0 = (z0 > 0.0f) ? 1.0f / z0 : 0.0f;
  float r1 = (z1 > 0.0f) ? 1.0f / z1 : 0.0f;
  float r2 = (z2 > 0.0f) ? 1.0f / z2 : 0.0f;
  float r3 = (z3 > 0.0f) ? 1.0f / z3 : 0.0f;

  float acc[ACC];
#pragma unroll
  for (int q = 0; q < ACC; ++q) acc[q] = 0.0f;

  for (int b0 = 0; b0 < kd; b0 += 64) {
    int i = b0 + lane;
    int sx = 0; float w0 = 0, w1 = 0, w2 = 0, w3 = 0;
    if (i < kd) {
      int ent = csr[o0 + i];
      sx = ent & (N_NODES - 1);
      int tt = (ent >> 16) & 15;
      const float4 sv = *reinterpret_cast<const float4*>(s_src + (size_t)sx * 4);
      w0 = __expf(lrelu(sv.x + sd0 + se[tt * 4 + 0]) - m0) * r0;
      w1 = __expf(lrelu(sv.y + sd1 + se[tt * 4 + 1]) - m1) * r1;
      w2 = __expf(lrelu(sv.z + sd2 + se[tt * 4 + 2]) - m2) * r2;
      w3 = __expf(lrelu(sv.w + sd3 + se[tt * 4 + 3]) - m3) * r3;
    }
    int cnt = min(64, kd - b0);
    for (int e = 0; e < cnt; ++e) {
      int se_ = __shfl(sx, e, 64);
      float u0 = __shfl(w0, e, 64), u1 = __shfl(w1, e, 64);
      float u2 = __shfl(w2, e, 64), u3 = __shfl(w3, e, 64);
      const TI* row = hin + (size_t)se_ * DIN;
      if constexpr (DIN == 128) {
        float v0 = tof(row[lane]);
        float v1 = tof(row[64 + lane]);
        acc[0] += u0 * v0; acc[1] += u0 * v1;
        acc[2] += u1 * v0; acc[3] += u1 * v1;
        acc[4] += u2 * v0; acc[5] += u2 * v1;
        acc[6] += u3 * v0; acc[7] += u3 * v1;
      } else if constexpr (DIN == 32) {
        float v = tof(row[lane & 31]);
        bool hi = lane >= 32;
        float wa = hi ? u1 : u0;
        float wb = hi ? u3 : u2;
        acc[0] += wa * v; acc[1] += wb * v;
      } else {
        float v = tof(row[lane & 15]);
        int hh = lane >> 4;
        float wa = (hh == 0) ? u0 : (hh == 1) ? u1 : (hh == 2) ? u2 : u3;
        acc[0] += wa * v;
      }
    }
  }

  TO* ar = agg + (size_t)n * (4 * DIN);
  if constexpr (DIN == 128) {
#pragma unroll
    for (int h = 0; h < 4; ++h) {
      ar[h * 128 + lane]      = (TO)acc[2 * h];
      ar[h * 128 + 64 + lane] = (TO)acc[2 * h + 1];
    }
  } else if constexpr (DIN == 32) {
    ar[lane]      = (TO)acc[0];   // (h=lane>>5)*32 + (lane&31) == lane
    ar[64 + lane] = (TO)acc[1];
  } else {
    ar[lane] = (TO)acc[0];        // (lane>>4)*16 + (lane&15) == lane
  }
}

// ---------- fp32 GEMM (layer 1 only; K=64, DOUT=32) ----------
template <int BM, int BN, int BK, int TM, int TN, int NT, int DIN, int DOUT, bool RELU>
__global__ __launch_bounds__(NT) void k_gemm(const float* __restrict__ A,
                                             const float* __restrict__ W,
                                             const float* __restrict__ bias,
                                             float* __restrict__ out) {
  constexpr int K = 4 * DIN;
  constexpr int LDA = BM + 4;
  constexpr int LDB = BN + 4;
  __shared__ __align__(16) float As[BK * LDA];   // transposed: As[k][m]
  __shared__ __align__(16) float Bs[BK * LDB];
  const int tid = threadIdx.x;
  const int tx = tid % (BN / TN);
  const int ty = tid / (BN / TN);
  const int mb = blockIdx.y * BM;
  const int jb = blockIdx.x * BN;
  float acc[TM][TN] = {};
  constexpr int ITA = (BM * BK) / (NT * 4);
  constexpr int ITB = (BK * BN) / (NT * 4);
  for (int kb = 0; kb < K; kb += BK) {
#pragma unroll
    for (int it = 0; it < ITA; ++it) {
      int f = it * NT * 4 + tid * 4;
      int r = f / BK, c = f % BK;
      float4 u = *reinterpret_cast<const float4*>(A + (size_t)(mb + r) * K + kb + c);
      As[(c + 0) * LDA + r] = u.x;
      As[(c + 1) * LDA + r] = u.y;
      As[(c + 2) * LDA + r] = u.z;
      As[(c + 3) * LDA + r] = u.w;
    }
#pragma unroll
    for (int it = 0; it < ITB; ++it) {
      int f = it * NT * 4 + tid * 4;
      int kk = f / BN, jj = f % BN;
      int k = kb + kk; int h = k / DIN; int i = k % DIN;
      float4 u = *reinterpret_cast<const float4*>(W + (size_t)i * 4 * DOUT + h * DOUT + jb + jj);
      Bs[kk * LDB + jj + 0] = u.x;
      Bs[kk * LDB + jj + 1] = u.y;
      Bs[kk * LDB + jj + 2] = u.z;
      Bs[kk * LDB + jj + 3] = u.w;
    }
    __syncthreads();
#pragma unroll
    for (int kk = 0; kk < BK; ++kk) {
      float a_[TM], b_[TN];
#pragma unroll
      for (int q = 0; q < TM / 4; ++q) {
        float4 v = *reinterpret_cast<const float4*>(&As[kk * LDA + ty * TM + q * 4]);
        a_[q * 4 + 0] = v.x; a_[q * 4 + 1] = v.y; a_[q * 4 + 2] = v.z; a_[q * 4 + 3] = v.w;
      }
#pragma unroll
      for (int q = 0; q < TN / 4; ++q) {
        float4 v = *reinterpret_cast<const float4*>(&Bs[kk * LDB + tx * TN + q * 4]);
        b_[q * 4 + 0] = v.x; b_[q * 4 + 1] = v.y; b_[q * 4 + 2] = v.z; b_[q * 4 + 3] = v.w;
      }
#pragma unroll
      for (int ii = 0; ii < TM; ++ii)
#pragma unroll
        for (int jj = 0; jj < TN; ++jj)
          acc[ii][jj] = fmaf(a_[ii], b_[jj], acc[ii][jj]);
    }
    __syncthreads();
  }
#pragma unroll
  for (int ii = 0; ii < TM; ++ii) {
    int m = mb + ty * TM + ii;
#pragma unroll
    for (int jj = 0; jj < TN; ++jj) {
      int j = jb + tx * TN + jj;
      float v = acc[ii][jj] * 0.25f + bias[j];
      if (RELU) v = fmaxf(v, 0.0f);
      if (!isfinite(v)) v = 0.0f;      // diagnostic guard; no-op when correct
      out[(size_t)m * DOUT + j] = v;
    }
  }
}

// ---------- fp16 MFMA GEMM (layers 2-3): out = act(0.25*A@Bt^T + bias) ----------
// A[m][k] fp16, Bt[j][k] fp16.  128x128 tile, 4 waves x (4x4) 16x16x32 frags.
// Frag layouts (verified in round 6): A[m=lane&15][k=quad*8+j]; B mirrors;
// C/D col=lane&15, row=quad*4+reg.
template <int K, int DOUT, bool RELU, typename TO>
__global__ __launch_bounds__(256) void k_gemm_mfma(const _Float16* __restrict__ A,
                                                   const _Float16* __restrict__ Bt,
                                                   const float* __restrict__ bias,
                                                   TO* __restrict__ out) {
  constexpr int BM = 128, BK = 32;
  constexpr int LD = BK + 8;                 // 40 halves: <=2-way banks (free)
  __shared__ _Float16 As[BM * LD];           // 10 KB
  __shared__ _Float16 Bs[BM * LD];           // 10 KB
  const int tid = threadIdx.x;
  const int lane = tid & 63, wv = tid >> 6;
  const int quad = lane >> 4, l16 = lane & 15;
  const int wm = (wv >> 1) * 64, wn = (wv & 1) * 64;
  const int mb = blockIdx.y * BM, jb = blockIdx.x * BM;

  f32x4 acc[4][4] = {};
  float bv[4];
#pragma unroll
  for (int fj = 0; fj < 4; ++fj) bv[fj] = bias[jb + wn + fj * 16 + l16];

  for (int kb = 0; kb < K; kb += BK) {
    __syncthreads();
#pragma unroll
    for (int it = 0; it < 2; ++it) {       // 512 x 16B loads each matrix
      int idx = it * 256 + tid;
      int r = idx >> 2, cq = (idx & 3) * 8;
      *reinterpret_cast<f16x8*>(&As[r * LD + cq]) =
          *reinterpret_cast<const f16x8*>(A + (size_t)(mb + r) * K + kb + cq);
      *reinterpret_cast<f16x8*>(&Bs[r * LD + cq]) =
          *reinterpret_cast<const f16x8*>(Bt + (size_t)(jb + r) * K + kb + cq);
    }
    __syncthreads();
    f16x8 af[4], bf[4];
#pragma unroll
    for (int f = 0; f < 4; ++f) {
      af[f] = *reinterpret_cast<const f16x8*>(&As[(wm + f * 16 + l16) * LD + quad * 8]);
      bf[f] = *reinterpret_cast<const f16x8*>(&Bs[(wn + f * 16 + l16) * LD + quad * 8]);
    }
#pragma unroll
    for (int fi = 0; fi < 4; ++fi)
#pragma unroll
      for (int fj = 0; fj < 4; ++fj)
        acc[fi][fj] = __builtin_amdgcn_mfma_f32_16x16x32_f16(af[fi], bf[fj], acc[fi][fj], 0, 0, 0);
  }
#pragma unroll
  for (int fi = 0; fi < 4; ++fi)
#pragma unroll
    for (int reg = 0; reg < 4; ++reg) {
      int m = mb + wm + fi * 16 + quad * 4 + reg;
#pragma unroll
      for (int fj = 0; fj < 4; ++fj) {
        int j = jb + wn + fj * 16 + l16;
        float v = acc[fi][fj][reg] * 0.25f + bv[fj];
        if (RELU) v = fmaxf(v, 0.0f);
        if (!isfinite(v)) v = 0.0f;
        out[(size_t)m * DOUT + j] = (TO)v;
      }
    }
}

// ---------- launch ----------
extern "C" void kernel_launch(void* const* d_in, const int* in_sizes, int n_in,
                              void* d_out, int out_size, void* d_ws, size_t ws_size,
                              hipStream_t stream) {
  (void)in_sizes; (void)n_in; (void)out_size; (void)ws_size;
  const float* x   = (const float*)d_in[0];
  const int*   ei  = (const int*)d_in[1];
  const float* W1  = (const float*)d_in[2];
  const float* We1 = (const float*)d_in[3];
  const float* as1 = (const float*)d_in[4];
  const float* ad1 = (const float*)d_in[5];
  const float* ae1 = (const float*)d_in[6];
  const float* b1  = (const float*)d_in[7];
  const float* W2  = (const float*)d_in[8];
  const float* We2 = (const float*)d_in[9];
  const float* as2 = (const float*)d_in[10];
  const float* ad2 = (const float*)d_in[11];
  const float* ae2 = (const float*)d_in[12];
  const float* b2  = (const float*)d_in[13];
  const float* W3  = (const float*)d_in[14];
  const float* We3 = (const float*)d_in[15];
  const float* as3 = (const float*)d_in[16];
  const float* ad3 = (const float*)d_in[17];
  const float* ae3 = (const float*)d_in[18];
  const float* b3  = (const float*)d_in[19];

  // workspace layout (~66 MB of the 256 MB ws; 256B-aligned offsets)
  char* p = (char*)d_ws;
  int* ofs       = (int*)(p + 0);              // (N+1)*4 -> reserve 131328
  int* deg       = (int*)(p + 131328);         // 131072
  int* cur       = (int*)(p + 262400);         // 131072
  int* csr       = (int*)(p + 393472);         // 655360
  float* ssrc    = (float*)(p + 1048832);      // 524288   [N][4]
  float* sdst    = (float*)(p + 1573120);      // 524288   [N][4]
  float* prep    = (float*)(p + 2097408);      // 4608
  float* h1      = (float*)(p + 2102016);      // 4194304  [N][32] f32
  _Float16* h2   = (_Float16*)(p + 6296320);   // 8388608  [N][128] f16
  float* agg1    = (float*)(p + 14684928);     // 8388608  [N][64] f32
  _Float16* agg2 = (_Float16*)(p + 23073536);  // 8388608  [N][128] f16
  _Float16* agg3 = (_Float16*)(p + 31462144);  // 33554432 [N][512] f16
  _Float16* w2t  = (_Float16*)(p + 65016576);  // 32768    Bt2[128][128] f16
  _Float16* w3t  = (_Float16*)(p + 65049344);  // 524288   Bt3[512][512] f16
  // end: 65573632 B

  // ---- CSR by dst (shared by all 3 layers) ----
  hipMemsetAsync(deg, 0, N_NODES * 4, stream);
  k_deg <<<E_TOT / 256, 256, 0, stream>>>(ei, deg);
  k_scan<<<1, 1024, 0, stream>>>(deg, ofs, cur);
  k_fill<<<E_TOT / 256, 256, 0, stream>>>(ei, cur, csr);

  // ---- layer 1: din=16, dout=32, fp32 GEMM ----
  k_prep<<<(164 * 64 + 255) / 256, 256, 0, stream>>>(W1, We1, as1, ad1, ae1, prep, 16, 32);
  k_scores<float, 16><<<N_NODES / 4, 256, 0, stream>>>(x, prep, ssrc, sdst);
  k_attn_agg<float, 16, float><<<N_NODES / 4, 256, 0, stream>>>(x, csr, ofs, prep, ssrc, sdst, agg1);
  k_gemm<64, 32, 16, 4, 4, 128, 16, 32, true>
      <<<dim3(1, N_NODES / 64), 128, 0, stream>>>(agg1, W1, b1, h1);

  // ---- layer 2: din=32, dout=128, fp16 MFMA (unchunked) ----
  k_prep<<<(292 * 64 + 255) / 256, 256, 0, stream>>>(W2, We2, as2, ad2, ae2, prep, 32, 128);
  k_wt<<<dim3(2, 2), 256, 0, stream>>>(W2, w2t, 32, 128);
  k_scores<float, 32><<<N_NODES / 4, 256, 0, stream>>>(h1, prep, ssrc, sdst);
  k_attn_agg<float, 32, _Float16><<<N_NODES / 4, 256, 0, stream>>>(h1, csr, ofs, prep, ssrc, sdst, agg2);
  k_gemm_mfma<128, 128, true, _Float16>
      <<<dim3(1, N_NODES / 128), 256, 0, stream>>>(agg2, w2t, b2, h2);

  // ---- layer 3: din=128, dout=512 (no relu), fp16 MFMA (unchunked) ----
  k_prep<<<(1060 * 64 + 255) / 256, 256, 0, stream>>>(W3, We3, as3, ad3, ae3, prep, 128, 512);
  k_wt<<<dim3(8, 8), 256, 0, stream>>>(W3, w3t, 128, 512);
  k_scores<_Float16, 128><<<N_NODES / 4, 256, 0, stream>>>(h2, prep, ssrc, sdst);
  k_attn_agg<_Float16, 128, _Float16><<<N_NODES / 4, 256, 0, stream>>>(h2, csr, ofs, prep, ssrc, sdst, agg3);
  k_gemm_mfma<512, 512, false, float>
      <<<dim3(4, N_NODES / 128), 256, 0, stream>>>(agg3, w3t, b3, (float*)d_out);
}